// Round 1
// baseline (83.031 us; speedup 1.0000x reference)
//
#include <hip/hip_runtime.h>
#include <hip/hip_bf16.h>
#include <climits>
#include <cfloat>

// Sampler: B=256 rows, V=128000 vocab, fp32.
// Per row: greedy argmax (temp==0) OR top-k mask + gumbel-max sample
// via argmax over allowed set of (logits/temp - log(exp_noise)).
// Handles exp_noise==0: masked-position zero -> NaN in reference -> first
// such index wins; allowed-position zero -> +inf (natural via log(0)=-inf).

#define V_SIZE 128000
#define NV4 (V_SIZE / 4)
#define BLOCK 1024
#define NWAVES (BLOCK / 64)
#define CAP 4096
#define ZCAP 64
#define BOUND 10.0f

__device__ __forceinline__ unsigned fkey(float f) {
    unsigned b = __float_as_uint(f);
    return (b & 0x80000000u) ? ~b : (b | 0x80000000u);
}
__device__ __forceinline__ float fkey_inv(unsigned k) {
    unsigned b = (k & 0x80000000u) ? (k & 0x7fffffffu) : ~k;
    return __uint_as_float(b);
}

// argmax update, first-index tie-break (matches np/jnp argmax)
__device__ __forceinline__ void amax_upd(float& v, int& i, float nv, int ni) {
    if (nv > v || (nv == v && ni < i)) { v = nv; i = ni; }
}

__device__ __forceinline__ void block_argmax(float& v, int& i, float* s_rv, int* s_ri) {
    const int tid = threadIdx.x, lane = tid & 63, wv = tid >> 6;
    __syncthreads();  // protect s_rv/s_ri reuse across calls
#pragma unroll
    for (int off = 32; off > 0; off >>= 1) {
        float ov = __shfl_xor(v, off);
        int oi = __shfl_xor(i, off);
        amax_upd(v, i, ov, oi);
    }
    if (lane == 0) { s_rv[wv] = v; s_ri[wv] = i; }
    __syncthreads();
    if (tid < 64) {
        float vv = (lane < NWAVES) ? s_rv[lane] : -INFINITY;
        int ii = (lane < NWAVES) ? s_ri[lane] : INT_MAX;
#pragma unroll
        for (int off = 8; off > 0; off >>= 1) {
            float ov = __shfl_xor(vv, off);
            int oi = __shfl_xor(ii, off);
            amax_upd(vv, ii, ov, oi);
        }
        if (lane == 0) { s_rv[0] = vv; s_ri[0] = ii; }
    }
    __syncthreads();
    v = s_rv[0]; i = s_ri[0];
}

extern "C" __global__ void __launch_bounds__(BLOCK)
sampler_kernel(const float* __restrict__ logits, const float* __restrict__ temps,
               const int* __restrict__ topks, const float* __restrict__ noise,
               int* __restrict__ out) {
    const int row = blockIdx.x;
    const int tid = threadIdx.x;
    const float temp = temps[row];
    const int topk = topks[row];
    const float* __restrict__ lg = logits + (size_t)row * V_SIZE;
    const float* __restrict__ nz = noise + (size_t)row * V_SIZE;
    const float4* __restrict__ lg4 = reinterpret_cast<const float4*>(lg);
    const float4* __restrict__ nz4 = reinterpret_cast<const float4*>(nz);

    __shared__ float s_cval[CAP];
    __shared__ int s_cidx[CAP];
    __shared__ int s_zidx[ZCAP];
    __shared__ int s_ccount, s_zcount, s_nan, s_cnt;
    __shared__ float s_rv[NWAVES];
    __shared__ int s_ri[NWAVES];
    __shared__ float s_kth;

    const bool needTopk = (temp != 0.0f) && (topk > 0);

    if (tid == 0) { s_ccount = 0; s_zcount = 0; s_nan = INT_MAX; s_kth = -INFINITY; }
    __syncthreads();

    // ---- Phase 1: stream logits (max/argmax + candidates) and noise (zeros) ----
    float bmax = -INFINITY; int bidx = INT_MAX;
    for (int b = tid; b < NV4; b += BLOCK) {
        float4 lv = lg4[b];
        float l[4] = {lv.x, lv.y, lv.z, lv.w};
        const int i0 = b << 2;
#pragma unroll
        for (int c = 0; c < 4; ++c) {
            amax_upd(bmax, bidx, l[c], i0 + c);
            if (needTopk && l[c] > BOUND) {
                int p = atomicAdd(&s_ccount, 1);
                if (p < CAP) { s_cval[p] = l[c]; s_cidx[p] = i0 + c; }
            }
        }
        if (needTopk) {
            float4 nv = nz4[b];
            float nn[4] = {nv.x, nv.y, nv.z, nv.w};
#pragma unroll
            for (int c = 0; c < 4; ++c) {
                if (nn[c] == 0.0f) {
                    int p = atomicAdd(&s_zcount, 1);
                    if (p < ZCAP) s_zidx[p] = i0 + c;
                }
            }
        }
    }
    __syncthreads();

    // ---- Greedy argmax (needed for temp==0 rows) ----
    float gv = bmax; int gi = bidx;
    block_argmax(gv, gi, s_rv, s_ri);
    const int greedy = gi;

    if (temp == 0.0f) {
        if (tid == 0) out[row] = greedy;
        return;
    }

    int result;
    if (needTopk) {
        const int k = min(max(topk, 1), V_SIZE);
        const int n = s_ccount;
        float kthv = -INFINITY;
        bool cands_ok = (n <= CAP) && (n >= k);
        if (cands_ok) {
            // rank-select: k-th largest among candidates (all values > BOUND)
            for (int t = tid; t < n; t += BLOCK) {
                float v = s_cval[t];
                int g = 0, e = 0;
                for (int j = 0; j < n; ++j) {
                    float w = s_cval[j];  // LDS broadcast
                    g += (w > v) ? 1 : 0;
                    e += (w == v) ? 1 : 0;
                }
                if (g < k && g + e >= k) s_kth = v;  // unique value; benign multi-write
            }
            __syncthreads();
            kthv = s_kth;
            if (!(kthv > BOUND + 0.5f)) cands_ok = false;  // margin: ensure allowed⊆candidates
        }
        if (!cands_ok) {
            // exact bitwise radix-select of k-th largest over the full row (rare)
            unsigned prefix = 0u;
            for (int bit = 31; bit >= 0; --bit) {
                const unsigned T = prefix | (1u << bit);
                if (tid == 0) s_cnt = 0;
                __syncthreads();
                int local = 0;
                for (int b = tid; b < NV4; b += BLOCK) {
                    float4 lv = lg4[b];
                    local += (fkey(lv.x) >= T);
                    local += (fkey(lv.y) >= T);
                    local += (fkey(lv.z) >= T);
                    local += (fkey(lv.w) >= T);
                }
#pragma unroll
                for (int off = 32; off > 0; off >>= 1) local += __shfl_xor(local, off);
                if ((tid & 63) == 0) atomicAdd(&s_cnt, local);
                __syncthreads();
                const int cnt = s_cnt;
                __syncthreads();
                if (cnt >= k) prefix = T;
            }
            kthv = fkey_inv(prefix);
        }
        const float thr = kthv / temp;  // IEEE div: bit-identical to ref threshold

        // zero-noise positions at masked indices -> NaN in reference -> first index wins
        const int zn = min(s_zcount, ZCAP);
        for (int t = tid; t < zn; t += BLOCK) {
            const int z = s_zidx[t];
            const float sc = lg[z] / temp;
            if (sc < thr) atomicMin(&s_nan, z);
        }

        // gumbel argmax over allowed set
        float gb = -INFINITY; int gbi = INT_MAX;
        if (cands_ok) {
            for (int t = tid; t < n; t += BLOCK) {
                const float sc = s_cval[t] / temp;
                if (sc >= thr) {
                    const int ix = s_cidx[t];
                    const float g = sc - logf(nz[ix]);  // log(0)=-inf -> g=+inf
                    amax_upd(gb, gbi, g, ix);
                }
            }
        } else {
            for (int b = tid; b < NV4; b += BLOCK) {
                float4 lv = lg4[b];
                float4 nv = nz4[b];
                float l[4] = {lv.x, lv.y, lv.z, lv.w};
                float nn[4] = {nv.x, nv.y, nv.z, nv.w};
                const int i0 = b << 2;
#pragma unroll
                for (int c = 0; c < 4; ++c) {
                    const float sc = l[c] / temp;
                    if (sc >= thr) {
                        const float g = sc - logf(nn[c]);
                        amax_upd(gb, gbi, g, i0 + c);
                    }
                }
            }
        }
        block_argmax(gb, gbi, s_rv, s_ri);
        result = (s_nan != INT_MAX) ? s_nan : gbi;
    } else {
        // top_k == 0, temp > 0: unmasked gumbel over full row
        float gb = -INFINITY; int gbi = INT_MAX;
        for (int b = tid; b < NV4; b += BLOCK) {
            float4 lv = lg4[b];
            float4 nv = nz4[b];
            float l[4] = {lv.x, lv.y, lv.z, lv.w};
            float nn[4] = {nv.x, nv.y, nv.z, nv.w};
            const int i0 = b << 2;
#pragma unroll
            for (int c = 0; c < 4; ++c) {
                const float sc = l[c] / temp;
                const float g = sc - logf(nn[c]);  // noise==0 -> +inf, wins (matches ref inf)
                amax_upd(gb, gbi, g, i0 + c);
            }
        }
        block_argmax(gb, gbi, s_rv, s_ri);
        result = gbi;
    }
    if (tid == 0) out[row] = result;
}

extern "C" void kernel_launch(void* const* d_in, const int* in_sizes, int n_in,
                              void* d_out, int out_size, void* d_ws, size_t ws_size,
                              hipStream_t stream) {
    const float* logits = (const float*)d_in[0];
    const float* temps  = (const float*)d_in[1];
    const int*   topks  = (const int*)d_in[2];
    const float* noise  = (const float*)d_in[3];
    int* out = (int*)d_out;
    const int B = in_sizes[1];  // 256 rows
    // in_sizes[0] / B == 128000 == V_SIZE (fixed for this problem)
    sampler_kernel<<<B, BLOCK, 0, stream>>>(logits, temps, topks, noise, out);
}

// Round 2
// 70.639 us; speedup vs baseline: 1.1754x; 1.1754x over previous
//
#include <hip/hip_runtime.h>
#include <hip/hip_bf16.h>
#include <climits>
#include <cfloat>

// Sampler: B=256 rows, V=128000 vocab, fp32.
// Row types (uniform per block):
//   temp==0          -> greedy argmax over logits (noise not read)
//   temp>0 && topk>0 -> candidate scan (logit > BOUND) + noise-zero scan,
//                       exact k-th threshold, gumbel argmax over allowed set
//   temp>0 && topk==0-> full-row gumbel argmax
// Gumbel identity: argmax(probs/noise) == argmax(scaled - log(noise)) over
// allowed set. noise==0 at masked position -> 0/0=NaN in ref -> first such
// index wins; at allowed position -> +inf (falls out of log(0) = -inf).

#define V_SIZE 128000
#define NV4 (V_SIZE / 4)
#define BLOCK 1024
#define NWAVES (BLOCK / 64)
#define CAP 4096
#define ZCAP 64
#define BOUND 10.0f

__device__ __forceinline__ unsigned fkey(float f) {
    unsigned b = __float_as_uint(f);
    return (b & 0x80000000u) ? ~b : (b | 0x80000000u);
}
__device__ __forceinline__ float fkey_inv(unsigned k) {
    unsigned b = (k & 0x80000000u) ? (k & 0x7fffffffu) : ~k;
    return __uint_as_float(b);
}

__device__ __forceinline__ void amax_upd(float& v, int& i, float nv, int ni) {
    if (nv > v || (nv == v && ni < i)) { v = nv; i = ni; }
}

__device__ __forceinline__ void block_argmax(float& v, int& i, float* s_rv, int* s_ri) {
    const int tid = threadIdx.x, lane = tid & 63, wv = tid >> 6;
    __syncthreads();
#pragma unroll
    for (int off = 32; off > 0; off >>= 1) {
        float ov = __shfl_xor(v, off);
        int oi = __shfl_xor(i, off);
        amax_upd(v, i, ov, oi);
    }
    if (lane == 0) { s_rv[wv] = v; s_ri[wv] = i; }
    __syncthreads();
    if (tid < 64) {
        float vv = (lane < NWAVES) ? s_rv[lane] : -INFINITY;
        int ii = (lane < NWAVES) ? s_ri[lane] : INT_MAX;
#pragma unroll
        for (int off = 8; off > 0; off >>= 1) {
            float ov = __shfl_xor(vv, off);
            int oi = __shfl_xor(ii, off);
            amax_upd(vv, ii, ov, oi);
        }
        if (lane == 0) { s_rv[0] = vv; s_ri[0] = ii; }
    }
    __syncthreads();
    v = s_rv[0]; i = s_ri[0];
}

// argmax over one float4; strict > keeps earliest index (ascending scan order)
__device__ __forceinline__ void amax4(float4 v, int b, float& bmax, int& bidx) {
    const float m = fmaxf(fmaxf(v.x, v.y), fmaxf(v.z, v.w));
    if (m > bmax) {
        const int i0 = b << 2;
        bmax = m;
        bidx = (v.x == m) ? i0 : (v.y == m) ? i0 + 1 : (v.z == m) ? i0 + 2 : i0 + 3;
    }
}

__device__ __forceinline__ void cand4(float4 v, int b, float* s_cval, int* s_cidx,
                                      int* s_ccount) {
    const float m = fmaxf(fmaxf(v.x, v.y), fmaxf(v.z, v.w));
    if (m > BOUND) {  // rare (~0.6% of quads)
        const int i0 = b << 2;
        const float l[4] = {v.x, v.y, v.z, v.w};
#pragma unroll
        for (int c = 0; c < 4; ++c) {
            if (l[c] > BOUND) {
                int p = atomicAdd(s_ccount, 1);
                if (p < CAP) { s_cval[p] = l[c]; s_cidx[p] = i0 + c; }
            }
        }
    }
}

__device__ __forceinline__ void zero4(float4 v, int b, int* s_zidx, int* s_zcount) {
    const float mn = fminf(fminf(v.x, v.y), fminf(v.z, v.w));
    if (mn == 0.0f) {  // Exp(1) noise >= 0, so min==0 iff a zero exists (very rare)
        const int i0 = b << 2;
        const float l[4] = {v.x, v.y, v.z, v.w};
#pragma unroll
        for (int c = 0; c < 4; ++c) {
            if (l[c] == 0.0f) {
                int p = atomicAdd(s_zcount, 1);
                if (p < ZCAP) s_zidx[p] = i0 + c;
            }
        }
    }
}

extern "C" __global__ void __launch_bounds__(BLOCK)
sampler_kernel(const float* __restrict__ logits, const float* __restrict__ temps,
               const int* __restrict__ topks, const float* __restrict__ noise,
               int* __restrict__ out) {
    const int row = blockIdx.x;
    const int tid = threadIdx.x;
    const float temp = temps[row];
    const int topk = topks[row];
    const float* __restrict__ lg = logits + (size_t)row * V_SIZE;
    const float* __restrict__ nz = noise + (size_t)row * V_SIZE;
    const float4* __restrict__ lg4 = reinterpret_cast<const float4*>(lg);
    const float4* __restrict__ nz4 = reinterpret_cast<const float4*>(nz);

    __shared__ float s_cval[CAP];
    __shared__ int s_cidx[CAP];
    __shared__ int s_zidx[ZCAP];
    __shared__ int s_ccount, s_zcount, s_nan, s_cnt;
    __shared__ float s_rv[NWAVES];
    __shared__ int s_ri[NWAVES];
    __shared__ float s_kth;

    // ---------------- temp == 0: greedy argmax only (noise never read) -------
    if (temp == 0.0f) {
        float bmax = -INFINITY; int bidx = INT_MAX;
        int b = tid;
        for (; b + 3 * BLOCK < NV4; b += 4 * BLOCK) {
            float4 a0 = lg4[b];
            float4 a1 = lg4[b + BLOCK];
            float4 a2 = lg4[b + 2 * BLOCK];
            float4 a3 = lg4[b + 3 * BLOCK];
            amax4(a0, b, bmax, bidx);
            amax4(a1, b + BLOCK, bmax, bidx);
            amax4(a2, b + 2 * BLOCK, bmax, bidx);
            amax4(a3, b + 3 * BLOCK, bmax, bidx);
        }
        for (; b < NV4; b += BLOCK) amax4(lg4[b], b, bmax, bidx);
        block_argmax(bmax, bidx, s_rv, s_ri);
        if (tid == 0) out[row] = bidx;
        return;
    }

    if (tid == 0) { s_ccount = 0; s_zcount = 0; s_nan = INT_MAX; s_kth = -INFINITY; }
    __syncthreads();

    int result;
    if (topk > 0) {
        // ---- scan 1: logits -> candidates (values > BOUND) ----
        int b = tid;
        for (; b + 3 * BLOCK < NV4; b += 4 * BLOCK) {
            float4 a0 = lg4[b];
            float4 a1 = lg4[b + BLOCK];
            float4 a2 = lg4[b + 2 * BLOCK];
            float4 a3 = lg4[b + 3 * BLOCK];
            cand4(a0, b, s_cval, s_cidx, &s_ccount);
            cand4(a1, b + BLOCK, s_cval, s_cidx, &s_ccount);
            cand4(a2, b + 2 * BLOCK, s_cval, s_cidx, &s_ccount);
            cand4(a3, b + 3 * BLOCK, s_cval, s_cidx, &s_ccount);
        }
        for (; b < NV4; b += BLOCK) cand4(lg4[b], b, s_cval, s_cidx, &s_ccount);

        // ---- scan 2: noise -> exact-zero positions ----
        b = tid;
        for (; b + 3 * BLOCK < NV4; b += 4 * BLOCK) {
            float4 a0 = nz4[b];
            float4 a1 = nz4[b + BLOCK];
            float4 a2 = nz4[b + 2 * BLOCK];
            float4 a3 = nz4[b + 3 * BLOCK];
            zero4(a0, b, s_zidx, &s_zcount);
            zero4(a1, b + BLOCK, s_zidx, &s_zcount);
            zero4(a2, b + 2 * BLOCK, s_zidx, &s_zcount);
            zero4(a3, b + 3 * BLOCK, s_zidx, &s_zcount);
        }
        for (; b < NV4; b += BLOCK) zero4(nz4[b], b, s_zidx, &s_zcount);
        __syncthreads();

        const int k = min(max(topk, 1), V_SIZE);
        const int n = s_ccount;
        float kthv = -INFINITY;
        bool cands_ok = (n <= CAP) && (n >= k);
        if (cands_ok) {
            // rank-select k-th largest among candidates (O(n^2/BLOCK), LDS broadcast)
            for (int t = tid; t < n; t += BLOCK) {
                float v = s_cval[t];
                int g = 0, e = 0;
                for (int j = 0; j < n; ++j) {
                    float w = s_cval[j];
                    g += (w > v) ? 1 : 0;
                    e += (w == v) ? 1 : 0;
                }
                if (g < k && g + e >= k) s_kth = v;
            }
            __syncthreads();
            kthv = s_kth;
            if (!(kthv > BOUND + 0.5f)) cands_ok = false;  // allowed set must be subset of candidates
        }
        if (!cands_ok) {
            // exact bitwise radix-select over the full row (never expected to run)
            unsigned prefix = 0u;
            for (int bit = 31; bit >= 0; --bit) {
                const unsigned T = prefix | (1u << bit);
                if (tid == 0) s_cnt = 0;
                __syncthreads();
                int local = 0;
                for (int q = tid; q < NV4; q += BLOCK) {
                    float4 lv = lg4[q];
                    local += (fkey(lv.x) >= T);
                    local += (fkey(lv.y) >= T);
                    local += (fkey(lv.z) >= T);
                    local += (fkey(lv.w) >= T);
                }
#pragma unroll
                for (int off = 32; off > 0; off >>= 1) local += __shfl_xor(local, off);
                if ((tid & 63) == 0) atomicAdd(&s_cnt, local);
                __syncthreads();
                const int cnt = s_cnt;
                __syncthreads();
                if (cnt >= k) prefix = T;
            }
            kthv = fkey_inv(prefix);
        }
        const float thr = kthv / temp;  // IEEE div: bit-identical to ref threshold

        // masked position with zero noise -> NaN in ref -> first index wins
        const int zn = min(s_zcount, ZCAP);
        for (int t = tid; t < zn; t += BLOCK) {
            const int z = s_zidx[t];
            const float sc = lg[z] / temp;
            if (sc < thr) atomicMin(&s_nan, z);
        }

        // gumbel argmax over allowed set (scattered noise reads, ~k of them matter)
        float gb = -INFINITY; int gbi = INT_MAX;
        if (cands_ok) {
            for (int t = tid; t < n; t += BLOCK) {
                const float sc = s_cval[t] / temp;
                if (sc >= thr) {
                    const int ix = s_cidx[t];
                    const float g = sc - logf(nz[ix]);  // log(0) = -inf -> +inf
                    amax_upd(gb, gbi, g, ix);
                }
            }
        } else {
            for (int q = tid; q < NV4; q += BLOCK) {
                float4 lv = lg4[q];
                float4 nv = nz4[q];
                const float l[4] = {lv.x, lv.y, lv.z, lv.w};
                const float nn[4] = {nv.x, nv.y, nv.z, nv.w};
                const int i0 = q << 2;
#pragma unroll
                for (int c = 0; c < 4; ++c) {
                    const float sc = l[c] / temp;
                    if (sc >= thr) {
                        const float g = sc - logf(nn[c]);
                        amax_upd(gb, gbi, g, i0 + c);
                    }
                }
            }
        }
        block_argmax(gb, gbi, s_rv, s_ri);
        result = (s_nan != INT_MAX) ? s_nan : gbi;
    } else {
        // ---- topk == 0, temp > 0: unmasked gumbel over the full row ----
        float gb = -INFINITY; int gbi = INT_MAX;
        for (int q = tid; q < NV4; q += BLOCK) {
            float4 lv = lg4[q];
            float4 nv = nz4[q];
            const float l[4] = {lv.x, lv.y, lv.z, lv.w};
            const float nn[4] = {nv.x, nv.y, nv.z, nv.w};
            const int i0 = q << 2;
#pragma unroll
            for (int c = 0; c < 4; ++c) {
                const float sc = l[c] / temp;
                const float g = sc - logf(nn[c]);  // noise==0 -> +inf, matches ref inf
                amax_upd(gb, gbi, g, i0 + c);
            }
        }
        block_argmax(gb, gbi, s_rv, s_ri);
        result = gbi;
    }
    if (tid == 0) out[row] = result;
}

extern "C" void kernel_launch(void* const* d_in, const int* in_sizes, int n_in,
                              void* d_out, int out_size, void* d_ws, size_t ws_size,
                              hipStream_t stream) {
    const float* logits = (const float*)d_in[0];
    const float* temps  = (const float*)d_in[1];
    const int*   topks  = (const int*)d_in[2];
    const float* noise  = (const float*)d_in[3];
    int* out = (int*)d_out;
    const int B = in_sizes[1];  // 256 rows
    sampler_kernel<<<B, BLOCK, 0, stream>>>(logits, temps, topks, noise, out);
}